// Round 11
// baseline (108.021 us; speedup 1.0000x reference)
//
#include <hip/hip_runtime.h>
#include <hip/hip_bf16.h>
#include <stdint.h>

typedef __bf16 bf16x8 __attribute__((ext_vector_type(8)));
typedef float f32x4 __attribute__((ext_vector_type(4)));

__device__ __forceinline__ uint16_t f32_to_bf16_rne(float f) {
    uint32_t u = __float_as_uint(f);
    u += 0x7fffu + ((u >> 16) & 1u);
    return (uint16_t)(u >> 16);
}

// Convert two fp32 arrays to bf16 (RNE) in one grid-stride kernel.
__global__ void cvt2_kernel(const float* __restrict__ a, long na4,
                            const float* __restrict__ b, long nb4,
                            uint16_t* __restrict__ oa, uint16_t* __restrict__ ob) {
    long i = (long)blockIdx.x * blockDim.x + threadIdx.x;
    const long stride = (long)gridDim.x * blockDim.x;
    const long tot = na4 + nb4;
    for (; i < tot; i += stride) {
        const float4* src; ushort4* dst; long j;
        if (i < na4) { src = (const float4*)a; dst = (ushort4*)oa; j = i; }
        else         { src = (const float4*)b; dst = (ushort4*)ob; j = i - na4; }
        float4 f = src[j];
        ushort4 o;
        o.x = f32_to_bf16_rne(f.x);
        o.y = f32_to_bf16_rne(f.y);
        o.z = f32_to_bf16_rne(f.z);
        o.w = f32_to_bf16_rne(f.w);
        dst[j] = o;
    }
}

// out = p0 + p1 (bias already folded into p0 by GEMM slice 0).
__global__ void reduce2_kernel(const float4* __restrict__ p0,
                               const float4* __restrict__ p1,
                               float4* __restrict__ out, long n4) {
    long i = (long)blockIdx.x * blockDim.x + threadIdx.x;
    const long stride = (long)gridDim.x * blockDim.x;
    for (; i < n4; i += stride) {
        float4 a = p0[i], b = p1[i], r;
        r.x = a.x + b.x; r.y = a.y + b.y; r.z = a.z + b.z; r.w = a.w + b.w;
        out[i] = r;
    }
}

// ---------------------------------------------------------------------------
// v2: 256x256 tile, wave 128x64 (LDS-read-minimal geometry), split-K x2,
// r10-style LOOSE schedule (the only schedule class that has won here):
// BK=32/phase, ring of 3 LDS regions x 32 KiB = 96 KiB
//   region: A[256r][32k] bf16 (16 KiB) + B[256r][32k] (16 KiB at +16384).
// 8 waves (2M x 4N), per-wave 128x64 output (acc 8x4 f32x4 = 128 VGPR).
// Phase p: barrier; READ12(region p%3); STAGE4(region (p+2)%3); MFMA32
// (same-phase consumption — compiler emits fine-grained lgkmcnt, m97-
// verified); vmcnt(4) at end (publishes region p+1 pre-barrier).
// No setprio / no sched_barrier (r10 A/B: pins cost).
// Swizzle: 128-B super-rows hold 2 tile-rows; 16-B chunk c of super-row sr
// at slot c ^ (sr&7) — r6/r7 refcheck-verified, measured 0 conflicts.
// Grid = 2 x (M/256) x (N/256); slice s -> partial P + s*M*N (slice 0 adds
// bias); reduce2 sums. Per-CU per phase: MFMA 1242 cyc > LDS reads ~750-1130
// -> MFMA-dominant (vs 64x64-wave geometry where LDS reads > MFMA).
// ---------------------------------------------------------------------------

#define GLD(gp, lp) __builtin_amdgcn_global_load_lds(                           \
    (const __attribute__((address_space(1))) uint32_t*)(gp),                    \
    (__attribute__((address_space(3))) uint32_t*)(void*)(lp), 16, 0, 0)

#define MM(a, b, c) __builtin_amdgcn_mfma_f32_16x16x32_bf16(a, b, c, 0, 0, 0)

// Stage one K32 region: 2 A-issues + 2 B-issues (4 vmcnt items/thread).
#define STAGE4(KB, RS) do {                                                     \
    GLD(pA0 + (KB), lds + (RS) + t16);                                          \
    GLD(pA1 + (KB), lds + (RS) + 8192  + t16);                                  \
    GLD(pB0 + (KB), lds + (RS) + 16384 + t16);                                  \
    GLD(pB1 + (KB), lds + (RS) + 16384 + 8192 + t16);                           \
} while (0)

// Read 8 A-frags + 4 B-frags of one region (base = ring pointer RB).
#define READ12(RB) do {                                                         \
    fa0 = *(const bf16x8*)((RB) + aof0);                                        \
    fa1 = *(const bf16x8*)((RB) + aof1);                                        \
    fa2 = *(const bf16x8*)((RB) + aof2);                                        \
    fa3 = *(const bf16x8*)((RB) + aof3);                                        \
    fa4 = *(const bf16x8*)((RB) + aof4);                                        \
    fa5 = *(const bf16x8*)((RB) + aof5);                                        \
    fa6 = *(const bf16x8*)((RB) + aof6);                                        \
    fa7 = *(const bf16x8*)((RB) + aof7);                                        \
    fb0 = *(const bf16x8*)((RB) + bof0);                                        \
    fb1 = *(const bf16x8*)((RB) + bof1);                                        \
    fb2 = *(const bf16x8*)((RB) + bof2);                                        \
    fb3 = *(const bf16x8*)((RB) + bof3);                                        \
} while (0)

#define MROW(AR, mi) do {                                                       \
    acc[mi][0] = MM(AR, fb0, acc[mi][0]);                                       \
    acc[mi][1] = MM(AR, fb1, acc[mi][1]);                                       \
    acc[mi][2] = MM(AR, fb2, acc[mi][2]);                                       \
    acc[mi][3] = MM(AR, fb3, acc[mi][3]);                                       \
} while (0)

#define MFMA32() do {                                                           \
    MROW(fa0, 0); MROW(fa1, 1); MROW(fa2, 2); MROW(fa3, 3);                     \
    MROW(fa4, 4); MROW(fa5, 5); MROW(fa6, 6); MROW(fa7, 7);                     \
} while (0)

#define ROT3() do { uint8_t* t_ = r0; r0 = r1; r1 = r2; r2 = t_; } while (0)

#define PHASEV2(STG, VM) do {                                                   \
    __builtin_amdgcn_s_barrier();                                               \
    READ12(r0);                                                                 \
    STG;                                                                        \
    MFMA32();                                                                   \
    VM;                                                                         \
    ROT3(); kk += 64;                                                           \
} while (0)

__global__ __launch_bounds__(512, 2) void gemm_v2_bf16(
    const uint16_t* __restrict__ A,   // M x K bf16 (x)
    const uint16_t* __restrict__ B,   // N x K bf16 (weight)
    const float* __restrict__ bias,
    float* __restrict__ P,            // partials: slice s at P + s*M*N
    int M, int N, int K)
{
    extern __shared__ __align__(16) uint8_t lds[];
    const int tid  = threadIdx.x;
    const int lane = tid & 63;
    const int wave = tid >> 6;
    const int wm = wave >> 2;   // 0..1 (M halves: 128 rows each)
    const int wc = wave & 3;    // 0..3 (N quarters: 64 cols each)

    // Bijective XCD-aware swizzle over the full grid.
    const int nwg = gridDim.x;
    int swz;
    {
        const int q = nwg >> 3, r = nwg & 7;
        const int xcd = blockIdx.x & 7, k = blockIdx.x >> 3;
        swz = (xcd < r ? xcd * (q + 1) : r * (q + 1) + (xcd - r) * q) + k;
    }
    const int MB = M >> 8;
    const int ntile = MB * (N >> 8);
    const int slice = swz / ntile;           // 0 or 1 (K half)
    const int tilei = swz % ntile;
    const int brow = tilei % MB;
    const int bcol = tilei / MB;
    const int Ksl = K >> 1;

    // ---- staging addressing (pre-swizzled global source, linear LDS dest).
    // Sub-area = 256 tile-rows x 32 k = 1024 chunks of 16 B = 128 super-rows.
    // Chunk ci: sr = ci>>3, slot = ci&7, global chunk c = slot ^ (sr&7),
    // tile-row = 2*sr + (c>>2), k-chunk = c&3.  Issue 1 (ci = 512+tid) is
    // exactly +128 tile-rows of issue 0 (512 is a multiple of 8).
    const int t16 = tid * 16;
    const size_t K2 = (size_t)K * 2;
    int row0, kb0;
    {
        const int sr = tid >> 3;
        const int c  = (tid & 7) ^ (sr & 7);
        row0 = 2 * sr + (c >> 2);
        kb0  = (c & 3) * 16;
    }
    const uint8_t* Ab = (const uint8_t*)A + (size_t)slice * Ksl * 2;
    const uint8_t* Bb = (const uint8_t*)B + (size_t)slice * Ksl * 2;
    const uint8_t* pA0 = Ab + (size_t)(brow * 256 + row0) * K2 + kb0;
    const uint8_t* pA1 = pA0 + (size_t)128 * K2;
    const uint8_t* pB0 = Bb + (size_t)(bcol * 256 + row0) * K2 + kb0;
    const uint8_t* pB1 = pB0 + (size_t)128 * K2;

    // ---- fragment read offsets (region-relative bytes), swizzled.
    // Lane (lm + 16 g) reads row rb+lm, k-chunk g:
    //   sr = r>>1, c = (r&1)*4 + g, byte = sr*128 + ((c ^ (sr&7))<<4).
    const int lm = lane & 15;
    const int g  = lane >> 4;
    int aof0, aof1, aof2, aof3, aof4, aof5, aof6, aof7, bof0, bof1, bof2, bof3;
    {
        int r, sr, c;
#define FOFF(DEST, RB, BASE) \
        r = (RB) + lm; sr = r >> 1; c = (r & 1) * 4 + g;                        \
        DEST = (BASE) + sr * 128 + ((c ^ (sr & 7)) << 4)
        FOFF(aof0, wm * 128 +   0, 0);
        FOFF(aof1, wm * 128 +  16, 0);
        FOFF(aof2, wm * 128 +  32, 0);
        FOFF(aof3, wm * 128 +  48, 0);
        FOFF(aof4, wm * 128 +  64, 0);
        FOFF(aof5, wm * 128 +  80, 0);
        FOFF(aof6, wm * 128 +  96, 0);
        FOFF(aof7, wm * 128 + 112, 0);
        FOFF(bof0, wc * 64 +   0, 16384);
        FOFF(bof1, wc * 64 +  16, 16384);
        FOFF(bof2, wc * 64 +  32, 16384);
        FOFF(bof3, wc * 64 +  48, 16384);
#undef FOFF
    }

    f32x4 acc[8][4];
#pragma unroll
    for (int m = 0; m < 8; ++m)
#pragma unroll
        for (int n = 0; n < 4; ++n)
            acc[m][n] = (f32x4){0.f, 0.f, 0.f, 0.f};

    // Single fragment set, same-phase consumption (compiler-managed lgkmcnt).
    bf16x8 fa0, fa1, fa2, fa3, fa4, fa5, fa6, fa7, fb0, fb1, fb2, fb3;

    const int nph = Ksl >> 5;     // K32 phases; launcher guarantees >= 4
    uint8_t* r0 = lds;
    uint8_t* r1 = lds + 32768;
    uint8_t* r2 = lds + 65536;
    size_t kk = 128;              // byte k-offset staged by current phase ((p+2)*64)

    // Prologue: stage regions 0,1; publish region 0 (wave-local drain; the
    // phase-0 barrier makes it block-wide).
    STAGE4(0, 0);
    STAGE4(64, 32768);
    asm volatile("s_waitcnt vmcnt(4)" ::: "memory");

    // Full phases 0 .. nph-3 (each stages region p+2, publishes region p+1).
    for (int p = 0; p <= nph - 3; ++p) {
        PHASEV2(STAGE4(kk, (uint32_t)(r2 - lds)),
                asm volatile("s_waitcnt vmcnt(4)" ::: "memory"));
    }
    // Phase nph-2: no stage; drain everything (publishes region nph-1).
    PHASEV2((void)0, asm volatile("s_waitcnt vmcnt(0)" ::: "memory"));
    // Phase nph-1: final region, no stage, no wait.
    __builtin_amdgcn_s_barrier();
    READ12(r0);
    MFMA32();

    // Epilogue: plain stores to this slice's partial buffer.
    float* Pq = P + (size_t)slice * ((size_t)M * N);
    const int crow0 = brow * 256 + wm * 128 + (lane >> 4) * 4;
    const int ccol0 = bcol * 256 + wc * 64 + lm;
#pragma unroll
    for (int nf = 0; nf < 4; ++nf) {
        const int col = ccol0 + nf * 16;
        const float bv = (slice == 0) ? bias[col] : 0.f;
#pragma unroll
        for (int mf = 0; mf < 8; ++mf) {
#pragma unroll
            for (int tt = 0; tt < 4; ++tt) {
                const int row = crow0 + mf * 16 + tt;
                Pq[(size_t)row * N + col] = acc[mf][nf][tt] + bv;
            }
        }
    }
}

// ---------------------------------------------------------------------------
// Fallback 1: r10-verified phase-lagged GEMM (73.2 us GEMM / 86.7 us total).
// ---------------------------------------------------------------------------
#define STAGE6(KOFF, BS) do {                                                   \
    GLD(pA0 + (KOFF), (BS) + t16);                                              \
    GLD(pA1 + (KOFF), (BS) + 8192  + t16);                                      \
    GLD(pB0 + (KOFF), (BS) + 16384 + t16);                                      \
    GLD(pB1 + (KOFF), (BS) + 24576 + t16);                                      \
    GLD(pB2 + (KOFF), (BS) + 32768 + t16);                                      \
    GLD(pB3 + (KOFF), (BS) + 40960 + t16);                                      \
} while (0)

#define READ8(P, BASE, SX) do {                                                 \
    P##a0 = *(const bf16x8*)((BASE) + (aoff0 ^ (SX)));                          \
    P##a1 = *(const bf16x8*)((BASE) + (aoff1 ^ (SX)));                          \
    P##a2 = *(const bf16x8*)((BASE) + (aoff2 ^ (SX)));                          \
    P##a3 = *(const bf16x8*)((BASE) + (aoff3 ^ (SX)));                          \
    P##b0 = *(const bf16x8*)((BASE) + (boff0 ^ (SX)));                          \
    P##b1 = *(const bf16x8*)((BASE) + (boff1 ^ (SX)));                          \
    P##b2 = *(const bf16x8*)((BASE) + (boff2 ^ (SX)));                          \
    P##b3 = *(const bf16x8*)((BASE) + (boff3 ^ (SX)));                          \
} while (0)

#define MFMA16(P) do {                                                          \
    acc[0][0] = MM(P##a0, P##b0, acc[0][0]); acc[0][1] = MM(P##a0, P##b1, acc[0][1]); \
    acc[0][2] = MM(P##a0, P##b2, acc[0][2]); acc[0][3] = MM(P##a0, P##b3, acc[0][3]); \
    acc[1][0] = MM(P##a1, P##b0, acc[1][0]); acc[1][1] = MM(P##a1, P##b1, acc[1][1]); \
    acc[1][2] = MM(P##a1, P##b2, acc[1][2]); acc[1][3] = MM(P##a1, P##b3, acc[1][3]); \
    acc[2][0] = MM(P##a2, P##b0, acc[2][0]); acc[2][1] = MM(P##a2, P##b1, acc[2][1]); \
    acc[2][2] = MM(P##a2, P##b2, acc[2][2]); acc[2][3] = MM(P##a2, P##b3, acc[2][3]); \
    acc[3][0] = MM(P##a3, P##b0, acc[3][0]); acc[3][1] = MM(P##a3, P##b1, acc[3][1]); \
    acc[3][2] = MM(P##a3, P##b2, acc[3][2]); acc[3][3] = MM(P##a3, P##b3, acc[3][3]); \
} while (0)

#define ROT3F() do { uint8_t* t_ = r0; r0 = r1; r1 = r2; r2 = t_; } while (0)

#define PHASE_FULLF(R, M) do {                                                  \
    __builtin_amdgcn_s_barrier();                                               \
    READ8(R##x, r0, 0);                                                         \
    MFMA16(M##x);                                                               \
    STAGE6(kk, r2);                                                             \
    READ8(R##y, r0, 64);                                                        \
    MFMA16(M##y);                                                               \
    asm volatile("s_waitcnt vmcnt(6)" ::: "memory");                            \
    ROT3F(); kk += 64;                                                          \
} while (0)

__global__ __launch_bounds__(512, 2) void gemm_pl_bf16(
    const uint16_t* __restrict__ A,
    const uint16_t* __restrict__ B,
    const float* __restrict__ bias,
    float* __restrict__ C, int M, int N, int K)
{
    extern __shared__ __align__(16) uint8_t lds[];
    const int tid  = threadIdx.x;
    const int lane = tid & 63;
    const int wave = tid >> 6;
    const int wr = wave >> 2;
    const int wc = wave & 3;

    const int nwg = gridDim.x;
    int swz;
    {
        const int q = nwg >> 3, r = nwg & 7;
        const int xcd = blockIdx.x & 7, k = blockIdx.x >> 3;
        swz = (xcd < r ? xcd * (q + 1) : r * (q + 1) + (xcd - r) * q) + k;
    }
    const int MB = M >> 7;
    const int brow = swz % MB;
    const int bcol = swz / MB;

    const int t16  = tid * 16;
    const int trow = tid >> 3;
    const int kc   = (tid & 7) ^ (trow & 7);
    const uint16_t* pA0 = A + (size_t)(brow * 128 + trow) * K + kc * 8;
    const uint16_t* pA1 = pA0 + (size_t)64 * K;
    const uint16_t* pB0 = B + (size_t)(bcol * 256 + trow) * K + kc * 8;
    const uint16_t* pB1 = pB0 + (size_t)64 * K;
    const uint16_t* pB2 = pB0 + (size_t)128 * K;
    const uint16_t* pB3 = pB0 + (size_t)192 * K;

    const int lm   = lane & 15;
    const int g    = lane >> 4;
    const int slot = (g ^ (lm & 7)) * 16;
    const int aoff0 = (wr * 64 +  0 + lm) * 128 + slot;
    const int aoff1 = (wr * 64 + 16 + lm) * 128 + slot;
    const int aoff2 = (wr * 64 + 32 + lm) * 128 + slot;
    const int aoff3 = (wr * 64 + 48 + lm) * 128 + slot;
    const int boff0 = 16384 + (wc * 64 +  0 + lm) * 128 + slot;
    const int boff1 = 16384 + (wc * 64 + 16 + lm) * 128 + slot;
    const int boff2 = 16384 + (wc * 64 + 32 + lm) * 128 + slot;
    const int boff3 = 16384 + (wc * 64 + 48 + lm) * 128 + slot;

    f32x4 acc[4][4];
#pragma unroll
    for (int m = 0; m < 4; ++m)
#pragma unroll
        for (int n = 0; n < 4; ++n)
            acc[m][n] = (f32x4){0.f, 0.f, 0.f, 0.f};

    bf16x8 exa0, exa1, exa2, exa3, exb0, exb1, exb2, exb3;
    bf16x8 eya0, eya1, eya2, eya3, eyb0, eyb1, eyb2, eyb3;
    bf16x8 oxa0, oxa1, oxa2, oxa3, oxb0, oxb1, oxb2, oxb3;
    bf16x8 oya0, oya1, oya2, oya3, oyb0, oyb1, oyb2, oyb3;

    const int nt = K >> 6;
    uint8_t* r0 = lds;
    uint8_t* r1 = lds + 49152;
    uint8_t* r2 = lds + 98304;
    size_t kk = 128;

    STAGE6(0, r0);
    STAGE6(64, r1);
    asm volatile("s_waitcnt vmcnt(6)" ::: "memory");

    __builtin_amdgcn_s_barrier();
    READ8(ex, r0, 0);
    STAGE6(kk, r2);
    READ8(ey, r0, 64);
    asm volatile("s_waitcnt vmcnt(6)" ::: "memory");
    ROT3F(); kk += 64;

    for (int p = 1; p + 1 <= nt - 3; p += 2) {
        PHASE_FULLF(o, e);
        PHASE_FULLF(e, o);
    }
    PHASE_FULLF(o, e);

    __builtin_amdgcn_s_barrier();
    READ8(ex, r0, 0);
    MFMA16(ox);
    READ8(ey, r0, 64);
    MFMA16(oy);
    asm volatile("s_waitcnt vmcnt(0)" ::: "memory");
    ROT3F();

    __builtin_amdgcn_s_barrier();
    READ8(ox, r0, 0);
    MFMA16(ex);
    READ8(oy, r0, 64);
    MFMA16(ey);

    MFMA16(ox);
    MFMA16(oy);

    const int crow0 = brow * 128 + wr * 64 + (lane >> 4) * 4;
    const int ccol0 = bcol * 256 + wc * 64 + lm;
#pragma unroll
    for (int nf = 0; nf < 4; ++nf) {
        const int col = ccol0 + nf * 16;
        const float bv = bias[col];
#pragma unroll
        for (int mf = 0; mf < 4; ++mf) {
#pragma unroll
            for (int tt = 0; tt < 4; ++tt) {
                const int row = crow0 + mf * 16 + tt;
                C[(size_t)row * N + col] = acc[mf][nf][tt] + bv;
            }
        }
    }
}

// Fallback 2: fp32 vector GEMM, one block per row.
__global__ void gemm_fallback(const float* __restrict__ x, const float* __restrict__ w,
                              const float* __restrict__ bias, float* __restrict__ out,
                              int M, int N, int K) {
    extern __shared__ float xs[];
    const int b = blockIdx.x;
    for (int k = threadIdx.x; k < K; k += blockDim.x) xs[k] = x[(size_t)b * K + k];
    __syncthreads();
    for (int j = threadIdx.x; j < N; j += blockDim.x) {
        const float* wr = w + (size_t)j * K;
        float s = 0.f;
        for (int k = 0; k < K; ++k) s += xs[k] * wr[k];
        out[(size_t)b * N + j] = s + bias[j];
    }
}

extern "C" void kernel_launch(void* const* d_in, const int* in_sizes, int n_in,
                              void* d_out, int out_size, void* d_ws, size_t ws_size,
                              hipStream_t stream) {
    const float* x    = (const float*)d_in[0];
    const float* w    = (const float*)d_in[1];
    const float* bias = (const float*)d_in[2];
    float* out = (float*)d_out;

    const int N = in_sizes[2];
    const int K = in_sizes[1] / N;
    const int M = in_sizes[0] / K;

    const size_t bf16_need = ((size_t)M * K + (size_t)N * K) * 2;
    const size_t part_need = (size_t)2 * (size_t)M * N * 4;

    if ((M % 256 == 0) && (N % 256 == 0) && (K % 256 == 0) && (K >= 256) &&
        ws_size >= bf16_need + part_need) {
        uint16_t* xb = (uint16_t*)d_ws;
        uint16_t* wb = xb + (size_t)M * K;
        float* P = (float*)(wb + (size_t)N * K);
        const long na4 = (long)M * K / 4, nb4 = (long)N * K / 4;
        cvt2_kernel<<<2048, 256, 0, stream>>>(x, na4, w, nb4, xb, wb);
        (void)hipFuncSetAttribute((const void*)gemm_v2_bf16,
                                  hipFuncAttributeMaxDynamicSharedMemorySize, 98304);
        dim3 grid(2 * (M / 256) * (N / 256));
        gemm_v2_bf16<<<grid, 512, 98304, stream>>>(xb, wb, bias, P, M, N, K);
        const long n4 = (long)M * N / 4;
        reduce2_kernel<<<2048, 256, 0, stream>>>((const float4*)P,
                                                 (const float4*)(P + (size_t)M * N),
                                                 (float4*)out, n4);
    } else if ((M % 128 == 0) && (N % 256 == 0) && (K % 128 == 0) && (K >= 256) &&
               ws_size >= bf16_need) {
        uint16_t* xb = (uint16_t*)d_ws;
        uint16_t* wb = xb + (size_t)M * K;
        const long na4 = (long)M * K / 4, nb4 = (long)N * K / 4;
        cvt2_kernel<<<2048, 256, 0, stream>>>(x, na4, w, nb4, xb, wb);
        (void)hipFuncSetAttribute((const void*)gemm_pl_bf16,
                                  hipFuncAttributeMaxDynamicSharedMemorySize, 147456);
        dim3 grid((M / 128) * (N / 256));
        gemm_pl_bf16<<<grid, 512, 147456, stream>>>(xb, wb, bias, out, M, N, K);
    } else {
        gemm_fallback<<<M, 256, (size_t)K * 4, stream>>>(x, w, bias, out, M, N, K);
    }
}

// Round 12
// 85.710 us; speedup vs baseline: 1.2603x; 1.2603x over previous
//
#include <hip/hip_runtime.h>
#include <hip/hip_bf16.h>
#include <stdint.h>

typedef __bf16 bf16x8 __attribute__((ext_vector_type(8)));
typedef float f32x4 __attribute__((ext_vector_type(4)));

__device__ __forceinline__ uint16_t f32_to_bf16_rne(float f) {
    uint32_t u = __float_as_uint(f);
    u += 0x7fffu + ((u >> 16) & 1u);
    return (uint16_t)(u >> 16);
}

// Convert two fp32 arrays to bf16 (RNE) in one grid-stride kernel.
__global__ void cvt2_kernel(const float* __restrict__ a, long na4,
                            const float* __restrict__ b, long nb4,
                            uint16_t* __restrict__ oa, uint16_t* __restrict__ ob) {
    long i = (long)blockIdx.x * blockDim.x + threadIdx.x;
    const long stride = (long)gridDim.x * blockDim.x;
    const long tot = na4 + nb4;
    for (; i < tot; i += stride) {
        const float4* src; ushort4* dst; long j;
        if (i < na4) { src = (const float4*)a; dst = (ushort4*)oa; j = i; }
        else         { src = (const float4*)b; dst = (ushort4*)ob; j = i - na4; }
        float4 f = src[j];
        ushort4 o;
        o.x = f32_to_bf16_rne(f.x);
        o.y = f32_to_bf16_rne(f.y);
        o.z = f32_to_bf16_rne(f.z);
        o.w = f32_to_bf16_rne(f.w);
        dst[j] = o;
    }
}

// ---------------------------------------------------------------------------
// r10-verified phase-lagged GEMM (session best: 73.2 us GEMM / 86.7 us total,
// MfmaUtil 40.6%, 0 bank conflicts).
// BM=128, BN=256, BK=64/phase, 8 waves (2M x 4N), wave 64x64 output.
// Ring of 3 LDS regions x 48 KiB = 144 KiB:
//   region: A[128r][64k] bf16 (16 KiB) + B[256r][64k] (32 KiB at +16384).
// Rows 128 B; 16-B chunk c of row r at slot c ^ (r&7) (measured 0-conflict).
// Phase p: barrier; read region p -> set S(p); MFMA set S(p-1); stage
// region p+2; vmcnt(6) (publishes region p+1 pre-barrier -> race-free).
// MFMA never depends on same-phase ds_reads (register double-buffer).
// No setprio (m190 + r10 A/B) and no sched_barrier pins (m141 + r10 A/B).
// ---------------------------------------------------------------------------

#define GLD(gp, lp) __builtin_amdgcn_global_load_lds(                           \
    (const __attribute__((address_space(1))) uint32_t*)(gp),                    \
    (__attribute__((address_space(3))) uint32_t*)(void*)(lp), 16, 0, 0)

#define MM(a, b, c) __builtin_amdgcn_mfma_f32_16x16x32_bf16(a, b, c, 0, 0, 0)

// Stage one K64 region (A: 2 issues, B: 4 issues; 6 vmcnt items/wave).
#define STAGE6(KOFF, BS) do {                                                   \
    GLD(pA0 + (KOFF), (BS) + t16);                                              \
    GLD(pA1 + (KOFF), (BS) + 8192  + t16);                                      \
    GLD(pB0 + (KOFF), (BS) + 16384 + t16);                                      \
    GLD(pB1 + (KOFF), (BS) + 24576 + t16);                                      \
    GLD(pB2 + (KOFF), (BS) + 32768 + t16);                                      \
    GLD(pB3 + (KOFF), (BS) + 40960 + t16);                                      \
} while (0)

// Read 4 A-frags + 4 B-frags (one K32 half; SX=0 -> k[0,32), SX=64 -> k[32,64)).
#define READ8(P, BASE, SX) do {                                                 \
    P##a0 = *(const bf16x8*)((BASE) + (aoff0 ^ (SX)));                          \
    P##a1 = *(const bf16x8*)((BASE) + (aoff1 ^ (SX)));                          \
    P##a2 = *(const bf16x8*)((BASE) + (aoff2 ^ (SX)));                          \
    P##a3 = *(const bf16x8*)((BASE) + (aoff3 ^ (SX)));                          \
    P##b0 = *(const bf16x8*)((BASE) + (boff0 ^ (SX)));                          \
    P##b1 = *(const bf16x8*)((BASE) + (boff1 ^ (SX)));                          \
    P##b2 = *(const bf16x8*)((BASE) + (boff2 ^ (SX)));                          \
    P##b3 = *(const bf16x8*)((BASE) + (boff3 ^ (SX)));                          \
} while (0)

#define MFMA16(P) do {                                                          \
    acc[0][0] = MM(P##a0, P##b0, acc[0][0]); acc[0][1] = MM(P##a0, P##b1, acc[0][1]); \
    acc[0][2] = MM(P##a0, P##b2, acc[0][2]); acc[0][3] = MM(P##a0, P##b3, acc[0][3]); \
    acc[1][0] = MM(P##a1, P##b0, acc[1][0]); acc[1][1] = MM(P##a1, P##b1, acc[1][1]); \
    acc[1][2] = MM(P##a1, P##b2, acc[1][2]); acc[1][3] = MM(P##a1, P##b3, acc[1][3]); \
    acc[2][0] = MM(P##a2, P##b0, acc[2][0]); acc[2][1] = MM(P##a2, P##b1, acc[2][1]); \
    acc[2][2] = MM(P##a2, P##b2, acc[2][2]); acc[2][3] = MM(P##a2, P##b3, acc[2][3]); \
    acc[3][0] = MM(P##a3, P##b0, acc[3][0]); acc[3][1] = MM(P##a3, P##b1, acc[3][1]); \
    acc[3][2] = MM(P##a3, P##b2, acc[3][2]); acc[3][3] = MM(P##a3, P##b3, acc[3][3]); \
} while (0)

#define ROT3() do { uint8_t* t_ = r0; r0 = r1; r1 = r2; r2 = t_; } while (0)

// Full phase: read set R from region r0, MFMA set M (read last phase),
// stage into r2, counted vmcnt at end (publishes region p+1).
#define PHASE_FULL(R, M) do {                                                   \
    __builtin_amdgcn_s_barrier();                                               \
    READ8(R##x, r0, 0);                                                         \
    MFMA16(M##x);                                                               \
    STAGE6(kk, r2);                                                             \
    READ8(R##y, r0, 64);                                                        \
    MFMA16(M##y);                                                               \
    asm volatile("s_waitcnt vmcnt(6)" ::: "memory");                            \
    ROT3(); kk += 64;                                                           \
} while (0)

__global__ __launch_bounds__(512, 2) void gemm_pl_bf16(
    const uint16_t* __restrict__ A,   // M x K bf16 (x)
    const uint16_t* __restrict__ B,   // N x K bf16 (weight)
    const float* __restrict__ bias,
    float* __restrict__ C, int M, int N, int K)
{
    extern __shared__ __align__(16) uint8_t lds[];
    const int tid  = threadIdx.x;
    const int lane = tid & 63;
    const int wave = tid >> 6;
    const int wr = wave >> 2;   // 0..1 (M)
    const int wc = wave & 3;    // 0..3 (N)

    // Bijective XCD-aware swizzle.
    const int nwg = gridDim.x;
    int swz;
    {
        const int q = nwg >> 3, r = nwg & 7;
        const int xcd = blockIdx.x & 7, k = blockIdx.x >> 3;
        swz = (xcd < r ? xcd * (q + 1) : r * (q + 1) + (xcd - r) * q) + k;
    }
    const int MB = M >> 7;
    const int brow = swz % MB;
    const int bcol = swz / MB;

    // Staging addressing (pre-swizzled global source, linear LDS dest).
    const int t16  = tid * 16;
    const int trow = tid >> 3;                       // 0..63
    const int kc   = (tid & 7) ^ (trow & 7);         // swizzled 16B-chunk index
    const uint16_t* pA0 = A + (size_t)(brow * 128 + trow) * K + kc * 8;
    const uint16_t* pA1 = pA0 + (size_t)64 * K;
    const uint16_t* pB0 = B + (size_t)(bcol * 256 + trow) * K + kc * 8;
    const uint16_t* pB1 = pB0 + (size_t)64 * K;
    const uint16_t* pB2 = pB0 + (size_t)128 * K;
    const uint16_t* pB3 = pB0 + (size_t)192 * K;

    // Fragment read offsets (region-relative), swizzled.
    const int lm   = lane & 15;
    const int g    = lane >> 4;
    const int slot = (g ^ (lm & 7)) * 16;
    const int aoff0 = (wr * 64 +  0 + lm) * 128 + slot;
    const int aoff1 = (wr * 64 + 16 + lm) * 128 + slot;
    const int aoff2 = (wr * 64 + 32 + lm) * 128 + slot;
    const int aoff3 = (wr * 64 + 48 + lm) * 128 + slot;
    const int boff0 = 16384 + (wc * 64 +  0 + lm) * 128 + slot;
    const int boff1 = 16384 + (wc * 64 + 16 + lm) * 128 + slot;
    const int boff2 = 16384 + (wc * 64 + 32 + lm) * 128 + slot;
    const int boff3 = 16384 + (wc * 64 + 48 + lm) * 128 + slot;

    f32x4 acc[4][4];
#pragma unroll
    for (int m = 0; m < 4; ++m)
#pragma unroll
        for (int n = 0; n < 4; ++n)
            acc[m][n] = (f32x4){0.f, 0.f, 0.f, 0.f};

    // Register fragment sets (E/O alternate by phase parity; x/y = K32 halves).
    bf16x8 exa0, exa1, exa2, exa3, exb0, exb1, exb2, exb3;
    bf16x8 eya0, eya1, eya2, eya3, eyb0, eyb1, eyb2, eyb3;
    bf16x8 oxa0, oxa1, oxa2, oxa3, oxb0, oxb1, oxb2, oxb3;
    bf16x8 oya0, oya1, oya2, oya3, oyb0, oyb1, oyb2, oyb3;

    const int nt = K >> 6;   // K64 phases; launcher guarantees even, >= 4
    uint8_t* r0 = lds;
    uint8_t* r1 = lds + 49152;
    uint8_t* r2 = lds + 98304;
    size_t kk = 128;         // k-element offset staged by the current phase

    // Prologue: stage regions 0,1; cover region 0.
    STAGE6(0, r0);
    STAGE6(64, r1);
    asm volatile("s_waitcnt vmcnt(6)" ::: "memory");

    // Phase 0 (reads E, no MFMA, stages region 2).
    __builtin_amdgcn_s_barrier();
    READ8(ex, r0, 0);
    STAGE6(kk, r2);
    READ8(ey, r0, 64);
    asm volatile("s_waitcnt vmcnt(6)" ::: "memory");
    ROT3(); kk += 64;

    // Pairs: phases 1..nt-4 (odd reads O / even reads E).
    for (int p = 1; p + 1 <= nt - 3; p += 2) {
        PHASE_FULL(o, e);
        PHASE_FULL(e, o);
    }
    // Phase nt-3 (odd): full.
    PHASE_FULL(o, e);

    // Phase nt-2 (even): no stage; drain remaining (region nt-1) pre-barrier.
    __builtin_amdgcn_s_barrier();
    READ8(ex, r0, 0);
    MFMA16(ox);
    READ8(ey, r0, 64);
    MFMA16(oy);
    asm volatile("s_waitcnt vmcnt(0)" ::: "memory");
    ROT3();

    // Phase nt-1 (odd): last reads.
    __builtin_amdgcn_s_barrier();
    READ8(ox, r0, 0);
    MFMA16(ex);
    READ8(oy, r0, 64);
    MFMA16(ey);

    // Final: consume the last-read set.
    MFMA16(ox);
    MFMA16(oy);

    // Epilogue: D mapping col = lane&15 (N), row = (lane>>4)*4 + t (M).
    const int crow0 = brow * 128 + wr * 64 + (lane >> 4) * 4;
    const int ccol0 = bcol * 256 + wc * 64 + lm;
#pragma unroll
    for (int nf = 0; nf < 4; ++nf) {
        const int col = ccol0 + nf * 16;
        const float bv = bias[col];
#pragma unroll
        for (int mf = 0; mf < 4; ++mf) {
#pragma unroll
            for (int tt = 0; tt < 4; ++tt) {
                const int row = crow0 + mf * 16 + tt;
                C[(size_t)row * N + col] = acc[mf][nf][tt] + bv;
            }
        }
    }
}

// ---------------------------------------------------------------------------
// Fallback 1: verified m97-structure 128x128 kernel.
// ---------------------------------------------------------------------------
__global__ __launch_bounds__(256) void gemm_bf16_kernel(
    const uint16_t* __restrict__ A,
    const uint16_t* __restrict__ B,
    const float* __restrict__ bias,
    float* __restrict__ C, int M, int N, int K)
{
    __shared__ __align__(16) uint16_t Alds[128 * 32];
    __shared__ __align__(16) uint16_t Blds[128 * 32];

    const int tid  = threadIdx.x;
    const int lane = tid & 63;
    const int wave = tid >> 6;
    const int wm = wave >> 1, wn = wave & 1;

    const int MBl = M >> 7;
    const int brow = blockIdx.x % MBl;
    const int bcol = blockIdx.x / MBl;

    const int off0 = wave * 1024 + lane * 16;
    const int row0 = off0 >> 6;
    const int colb = off0 & 63;

    const uint8_t* gA0 = (const uint8_t*)A + ((size_t)(brow * 128 + row0) * K) * 2 + colb;
    const uint8_t* gA1 = gA0 + (size_t)64 * K * 2;
    const uint8_t* gB0 = (const uint8_t*)B + ((size_t)(bcol * 128 + row0) * K) * 2 + colb;
    const uint8_t* gB1 = gB0 + (size_t)64 * K * 2;

    uint32_t* lA0 = (uint32_t*)((uint8_t*)Alds + off0);
    uint32_t* lA1 = (uint32_t*)((uint8_t*)Alds + off0 + 4096);
    uint32_t* lB0 = (uint32_t*)((uint8_t*)Blds + off0);
    uint32_t* lB1 = (uint32_t*)((uint8_t*)Blds + off0 + 4096);

#define STAGE_OLD() do {                                                                   \
    __builtin_amdgcn_global_load_lds((const __attribute__((address_space(1))) uint32_t*)gA0, \
                                     (__attribute__((address_space(3))) uint32_t*)lA0, 16, 0, 0); \
    __builtin_amdgcn_global_load_lds((const __attribute__((address_space(1))) uint32_t*)gA1, \
                                     (__attribute__((address_space(3))) uint32_t*)lA1, 16, 0, 0); \
    __builtin_amdgcn_global_load_lds((const __attribute__((address_space(1))) uint32_t*)gB0, \
                                     (__attribute__((address_space(3))) uint32_t*)lB0, 16, 0, 0); \
    __builtin_amdgcn_global_load_lds((const __attribute__((address_space(1))) uint32_t*)gB1, \
                                     (__attribute__((address_space(3))) uint32_t*)lB1, 16, 0, 0); \
    gA0 += 64; gA1 += 64; gB0 += 64; gB1 += 64;                                            \
} while (0)

    f32x4 acc[4][4];
#pragma unroll
    for (int mf = 0; mf < 4; ++mf)
#pragma unroll
        for (int nf = 0; nf < 4; ++nf)
            acc[mf][nf] = (f32x4){0.f, 0.f, 0.f, 0.f};

    const int nk = K >> 5;
    STAGE_OLD();

    const int arow = wm * 64 + (lane & 15);
    const int brw  = wn * 64 + (lane & 15);
    const int ke   = (lane >> 4) * 8;

    for (int kt = 0; kt < nk; ++kt) {
        __syncthreads();
        bf16x8 af[4], bfr[4];
#pragma unroll
        for (int mf = 0; mf < 4; ++mf)
            af[mf] = *(const bf16x8*)(&Alds[(arow + mf * 16) * 32 + ke]);
#pragma unroll
        for (int nf = 0; nf < 4; ++nf)
            bfr[nf] = *(const bf16x8*)(&Blds[(brw + nf * 16) * 32 + ke]);
        __syncthreads();
        if (kt + 1 < nk) STAGE_OLD();
#pragma unroll
        for (int mf = 0; mf < 4; ++mf)
#pragma unroll
            for (int nf = 0; nf < 4; ++nf)
                acc[mf][nf] = __builtin_amdgcn_mfma_f32_16x16x32_bf16(
                    af[mf], bfr[nf], acc[mf][nf], 0, 0, 0);
    }
#undef STAGE_OLD

    const int crow0 = brow * 128 + wm * 64 + (lane >> 4) * 4;
    const int ccol0 = bcol * 128 + wn * 64 + (lane & 15);
#pragma unroll
    for (int nf = 0; nf < 4; ++nf) {
        const int col = ccol0 + nf * 16;
        const float bv = bias[col];
#pragma unroll
        for (int mf = 0; mf < 4; ++mf) {
#pragma unroll
            for (int t = 0; t < 4; ++t) {
                const int row = crow0 + mf * 16 + t;
                C[(size_t)row * N + col] = acc[mf][nf][t] + bv;
            }
        }
    }
}

// Fallback 2: fp32 vector GEMM, one block per row.
__global__ void gemm_fallback(const float* __restrict__ x, const float* __restrict__ w,
                              const float* __restrict__ bias, float* __restrict__ out,
                              int M, int N, int K) {
    extern __shared__ float xs[];
    const int b = blockIdx.x;
    for (int k = threadIdx.x; k < K; k += blockDim.x) xs[k] = x[(size_t)b * K + k];
    __syncthreads();
    for (int j = threadIdx.x; j < N; j += blockDim.x) {
        const float* wr = w + (size_t)j * K;
        float s = 0.f;
        for (int k = 0; k < K; ++k) s += xs[k] * wr[k];
        out[(size_t)b * N + j] = s + bias[j];
    }
}

extern "C" void kernel_launch(void* const* d_in, const int* in_sizes, int n_in,
                              void* d_out, int out_size, void* d_ws, size_t ws_size,
                              hipStream_t stream) {
    const float* x    = (const float*)d_in[0];
    const float* w    = (const float*)d_in[1];
    const float* bias = (const float*)d_in[2];
    float* out = (float*)d_out;

    const int N = in_sizes[2];
    const int K = in_sizes[1] / N;
    const int M = in_sizes[0] / K;

    const size_t need = ((size_t)M * K + (size_t)N * K) * 2;
    const bool ws_ok = ws_size >= need;

    if ((M % 128 == 0) && (N % 256 == 0) && (K % 128 == 0) && (K >= 256) && ws_ok) {
        uint16_t* xb = (uint16_t*)d_ws;
        uint16_t* wb = xb + (size_t)M * K;
        const long na4 = (long)M * K / 4, nb4 = (long)N * K / 4;
        cvt2_kernel<<<2048, 256, 0, stream>>>(x, na4, w, nb4, xb, wb);
        (void)hipFuncSetAttribute((const void*)gemm_pl_bf16,
                                  hipFuncAttributeMaxDynamicSharedMemorySize, 147456);
        dim3 grid((M / 128) * (N / 256));
        gemm_pl_bf16<<<grid, 512, 147456, stream>>>(xb, wb, bias, out, M, N, K);
    } else if ((M % 128 == 0) && (N % 128 == 0) && (K % 32 == 0) && ws_ok) {
        uint16_t* xb = (uint16_t*)d_ws;
        uint16_t* wb = xb + (size_t)M * K;
        const long na4 = (long)M * K / 4, nb4 = (long)N * K / 4;
        cvt2_kernel<<<2048, 256, 0, stream>>>(x, na4, w, nb4, xb, wb);
        dim3 grid((M / 128) * (N / 128));
        gemm_bf16_kernel<<<grid, 256, 0, stream>>>(xb, wb, bias, out, M, N, K);
    } else {
        gemm_fallback<<<M, 256, (size_t)K * 4, stream>>>(x, w, bias, out, M, N, K);
    }
}